// Round 10
// baseline (723.593 us; speedup 1.0000x reference)
//
#include <hip/hip_runtime.h>
#include <stdint.h>

// Problem constants (from reference)
#define NN      5000
#define NB      8
#define TSTEPS  256
#define NDELAY  15
#define NW      157          // uint32 words covering 5000 presyn bits
#define NWPAD   160          // padded mask row (words 157..159 = 0)
#define NIPAD   5120         // padded neuron dim (columns of maskT2)
#define RW      160          // ring row words per (slot,b) = 640 bytes
#define NPB     8            // neurons per block
#define IPB     256          // 8 neurons x 8 batches x 4 K-quarters
#define NBLK    (NIPAD/NPB)  // 640 blocks; capacity 3/CU x 256 = 768 >= 640
#define RING_SLOTS 32
#define CH      4            // chunk length (64 chunks)
#define SPSTR   165          // s_spk row stride: banks 5b+8q+c all-distinct
#define NSUB    8            // arrive sub-counters per chunk

// Workspace layout (bytes)
#define MASK_BYTES (NWPAD*NIPAD*4)       // 3,276,800
#define BAR_OFF    MASK_BYTES
#define BAR_BYTES  (64*NSUB*16*4)        // 32,768
#define RING_OFF   (BAR_OFF + BAR_BYTES)
#define RING_BYTES (RING_SLOTS*NB*RW*4)  // 163,840
#define ZERO_BYTES (RING_OFF + RING_BYTES)

// ---------------------------------------------------------------------------
// Kernel 1: bit-pack connectivity, word-major-transposed:
//   maskT2[w*NIPAD + i] bit (j&31), w=j>>5, set iff W[i,j] != 0.
// ---------------------------------------------------------------------------
__global__ void _Brunel_build_mask(const float* __restrict__ W,
                                   uint32_t* __restrict__ maskT2)
{
    int j = blockIdx.x * blockDim.x + threadIdx.x;   // presyn 0..5119
    int i = blockIdx.y;                              // postsyn row 0..4999
    int lane = threadIdx.x & 63;
    bool nz = false;
    if (j < NN) nz = (W[(size_t)i * NN + j] != 0.0f);
    unsigned long long m = __ballot(nz);
    if ((lane & 31) == 0 && j < NN) {
        uint32_t wd = (lane == 0) ? (uint32_t)m : (uint32_t)(m >> 32);
        maskT2[(size_t)(j >> 5) * NIPAD + i] = wd;
    }
}

// ---------------------------------------------------------------------------
// Kernel 2: persistent SNN sim.
//  Block = 8 neurons x 8 batches x 4 K-quarters (256 thr, 640 blocks,
//  2.5 waves/SIMD). Mask: 8 rows in LDS, batch-shared (broadcast reads).
//  Lane (il,b,q): q-quarter words {0-39,40-79,80-119,120-156(+pad)}.
//  Packed accumulator acc = cE | cI<<16 via hoisted sh_hi; 2 shfl_xor
//  combine. Spike ring is byte-granular: block bb owns byte bb exactly.
//  Sync: round-8 coherence-point scheme (sc0sc1 ring/barc), per-chunk
//  arrive counters split over 8 lines.
// ---------------------------------------------------------------------------
__global__ void __launch_bounds__(IPB, 3) _Brunel_persist(
    const float* __restrict__ ext,
    const uint32_t* __restrict__ maskT2,
    uint32_t* __restrict__ ring,
    int* __restrict__ barc,
    float* __restrict__ out_spk,
    float* __restrict__ out_vs)
{
    const int tx   = threadIdx.x;
    const int wv   = tx >> 6;
    const int lane = tx & 63;
    const int il   = lane >> 5;            // 0..1
    const int b    = (lane >> 2) & 7;      // batch
    const int q    = lane & 3;             // K-quarter
    const int ilc  = wv * 2 + il;          // block-local neuron 0..7
    const int bb   = blockIdx.x;
    const int i    = bb * NPB + ilc;
    const bool act = (i < NN);

    __shared__ uint32_t s_mask[NPB][NWPAD];        //  5,120 B
    __shared__ uint32_t s_spk[CH * NB * SPSTR];    // 21,120 B
    __shared__ uint32_t s_bits[64];                //    256 B

    // ---- one-time: 8 mask rows -> LDS (pad words zeroed) ----
    {
        const int mil = tx & 7, w8 = tx >> 3;      // w8 0..31
        for (int pass = 0; pass < 5; ++pass) {
            int w = pass * 32 + w8;
            if (w < NWPAD) {
                uint32_t mv = 0;
                if (w < NW)
                    mv = maskT2[(size_t)w * NIPAD + (bb * NPB + mil)];
                s_mask[mil][w] = mv;
            }
        }
    }
    for (int idx = tx; idx < CH * NB * SPSTR; idx += IPB) s_spk[idx] = 0;
    __syncthreads();

    // per-lane K-segment: starts {0,40,80,120}; q==3 hi-words are inhibitory
    const int qstart = (q < 3) ? 40 * q : 120;
    const uint32_t sh_hi = (q == 3) ? 16u : 0u;
    const uint32_t* __restrict__ mrow = &s_mask[ilc][qstart];

    float v = 0.0f;

    for (int t0 = 0, m = 0; t0 < TSTEPS; t0 += CH, ++m) {
        // ---- prefetch external inputs (hides under poll/stage) ----
        float x0 = 0.f, x1 = 0.f, x2 = 0.f, x3 = 0.f;
        if (act) {
            const float* e0 = ext + ((size_t)t0 * NB + b) * NN + i;
            const size_t st = (size_t)NB * NN;
            x0 = e0[0]; x1 = e0[st]; x2 = e0[2 * st]; x3 = e0[3 * st];
        }

        // ---- wait for chunk m-3 (8 sub-counters), stage spike words ----
        if (m >= 3) {
            if (tx == 0) {
                const int base = (m - 3) * NSUB * 16;
                for (;;) {
                    int sacc = 0;
#pragma unroll
                    for (int u = 0; u < NSUB; ++u)
                        sacc += __hip_atomic_load(&barc[base + u * 16],
                                                  __ATOMIC_RELAXED,
                                                  __HIP_MEMORY_SCOPE_AGENT);
                    if (sacc >= NBLK) break;
                    __builtin_amdgcn_s_sleep(2);
                }
            }
            __syncthreads();
            const int ts0 = t0 - NDELAY;
            if (tx < NW) {
#pragma unroll
                for (int k = 0; k < CH; ++k) {
                    const int slot = (ts0 + k) & (RING_SLOTS - 1);
#pragma unroll
                    for (int b2 = 0; b2 < NB; ++b2) {
                        uint32_t wd = __hip_atomic_load(
                            &ring[((size_t)slot * NB + b2) * RW + tx],
                            __ATOMIC_RELAXED, __HIP_MEMORY_SCOPE_AGENT);
                        s_spk[(k * NB + b2) * SPSTR + tx] = wd;
                    }
                }
            }
            __syncthreads();
        }

        // ---- packed popc: acc = cE | cI<<16 over own 40-word quarter ----
        uint32_t acc0 = 0, acc1 = 0, acc2 = 0, acc3 = 0;
        const uint32_t* __restrict__ sp0 = &s_spk[(0 * NB + b) * SPSTR + qstart];
        const uint32_t* __restrict__ sp1 = &s_spk[(1 * NB + b) * SPSTR + qstart];
        const uint32_t* __restrict__ sp2 = &s_spk[(2 * NB + b) * SPSTR + qstart];
        const uint32_t* __restrict__ sp3 = &s_spk[(3 * NB + b) * SPSTR + qstart];
#pragma unroll 5
        for (int c = 0; c < 5; ++c) {      // words qstart+0..4: all excitatory
            uint32_t mw = mrow[c];
            acc0 += (uint32_t)__popc(mw & sp0[c]);
            acc1 += (uint32_t)__popc(mw & sp1[c]);
            acc2 += (uint32_t)__popc(mw & sp2[c]);
            acc3 += (uint32_t)__popc(mw & sp3[c]);
        }
#pragma unroll 5
        for (int c = 5; c < 40; ++c) {     // q<3: exc (sh 0); q==3: inh (<<16)
            uint32_t mw = mrow[c];
            acc0 += (uint32_t)__popc(mw & sp0[c]) << sh_hi;
            acc1 += (uint32_t)__popc(mw & sp1[c]) << sh_hi;
            acc2 += (uint32_t)__popc(mw & sp2[c]) << sh_hi;
            acc3 += (uint32_t)__popc(mw & sp3[c]) << sh_hi;
        }
        // combine the 4 K-quarters (lane bits 0..1)
        acc0 += __shfl_xor((int)acc0, 1); acc0 += __shfl_xor((int)acc0, 2);
        acc1 += __shfl_xor((int)acc1, 1); acc1 += __shfl_xor((int)acc1, 2);
        acc2 += __shfl_xor((int)acc2, 1); acc2 += __shfl_xor((int)acc2, 2);
        acc3 += __shfl_xor((int)acc3, 1); acc3 += __shfl_xor((int)acc3, 2);

        // ---- 4 sequential neuron updates (redundant across q; identical) ----
        uint32_t sbits = 0;
#define BRUNEL_STEP(kk, ACC, xk)                                              \
        {                                                                     \
            const int t = t0 + kk;                                            \
            int cE = (int)(ACC & 0xFFFFu);                                    \
            int cI = (int)(ACC >> 16);                                        \
            float cur = 0.1f * (float)cE - 0.5f * (float)cI;                  \
            v = v * 0.95f + (cur + xk);                                       \
            bool s = act && (v >= 1.0f);                                      \
            float vout = s ? 0.0f : v;                                        \
            if (act && q == 0) {                                              \
                size_t o = ((size_t)t * NB + b) * NN + i;                     \
                out_spk[o] = s ? 1.0f : 0.0f;                                 \
                out_vs[o]  = vout;                                            \
            }                                                                 \
            v = vout;                                                         \
            sbits |= (s ? 1u : 0u) << kk;                                     \
        }
        BRUNEL_STEP(0, acc0, x0)
        BRUNEL_STEP(1, acc1, x1)
        BRUNEL_STEP(2, acc2, x2)
        BRUNEL_STEP(3, acc3, x3)
#undef BRUNEL_STEP

        // ---- assemble spike bytes and publish to ring ----
        if (q == 0) s_bits[ilc * 8 + b] = sbits;
        __syncthreads();
        if (tx < 32 && bb < (NN / NPB)) {          // blocks 0..624 own byte bb
            const int k = tx >> 3, b2 = tx & 7;
            uint32_t byte = 0;
#pragma unroll
            for (int n2 = 0; n2 < 8; ++n2)
                byte |= ((s_bits[n2 * 8 + b2] >> k) & 1u) << n2;
            const int slot = (t0 + k) & (RING_SLOTS - 1);
            uint8_t* dst = (uint8_t*)ring + ((size_t)slot * NB + b2) * (RW * 4) + bb;
            __hip_atomic_store(dst, (uint8_t)byte,
                               __ATOMIC_RELAXED, __HIP_MEMORY_SCOPE_AGENT);
        }

        // ---- arrive: drain own stores, block barrier, sub-counter add ----
        asm volatile("s_waitcnt vmcnt(0)" ::: "memory");
        __syncthreads();
        if (tx == 0)
            __hip_atomic_fetch_add(&barc[(m * NSUB + (bb & 7)) * 16], 1,
                                   __ATOMIC_RELAXED, __HIP_MEMORY_SCOPE_AGENT);
    }
}

// ---------------------------------------------------------------------------
extern "C" void kernel_launch(void* const* d_in, const int* in_sizes, int n_in,
                              void* d_out, int out_size, void* d_ws, size_t ws_size,
                              hipStream_t stream)
{
    const float* ext = (const float*)d_in[0];   // [T,B,N] fp32
    const float* W   = (const float*)d_in[1];   // [N,N]   fp32

    float* out_spk = (float*)d_out;                          // [T,B,N]
    float* out_vs  = out_spk + (size_t)TSTEPS * NB * NN;     // [T,B,N]

    uint8_t*  ws   = (uint8_t*)d_ws;
    uint32_t* mask = (uint32_t*)(ws);
    int*      barc = (int*)(ws + BAR_OFF);
    uint32_t* ring = (uint32_t*)(ws + RING_OFF);

    // zero mask (pad columns must read 0) + per-chunk counters + ring
    hipMemsetAsync(ws, 0, ZERO_BYTES, stream);

    dim3 gmask(NIPAD / 256, NN);   // (20, 5000), 256 threads
    _Brunel_build_mask<<<gmask, 256, 0, stream>>>(W, mask);

    _Brunel_persist<<<NBLK, IPB, 0, stream>>>(ext, mask, ring, barc,
                                              out_spk, out_vs);
}

// Round 11
// 482.588 us; speedup vs baseline: 1.4994x; 1.4994x over previous
//
#include <hip/hip_runtime.h>
#include <stdint.h>

// Problem constants (from reference)
#define NN      5000
#define NB      8
#define TSTEPS  256
#define NDELAY  15
#define NW      157          // uint32 words covering 5000 presyn bits
#define NIPAD   5120         // padded neuron dim (columns of maskT2)
#define RW      160          // ring row stride in words (640 B, even -> 8B ok)
#define IPB     256          // threads per block
#define BPB     20           // blocks per batch
#define NBLK    (NB*BPB)     // 160 blocks -> 1 per CU, co-resident
#define RING_SLOTS 32
#define CH      4            // chunk length (64 chunks)
#define NCHUNK  (TSTEPS/CH)  // 64
#define BARSTRIDE 16         // ints between chunk counters (64B apart)

// Workspace layout (bytes)
#define MASK_BYTES (RW*NIPAD*4)          // 3,276,800
#define BAR_OFF    MASK_BYTES
#define BAR_BYTES  (64*BARSTRIDE*4)      // 4,096 (64 chunk counters)
#define RING_OFF   (BAR_OFF + BAR_BYTES)
#define RING_BYTES (RING_SLOTS*NB*RW*4)  // 163,840
#define ZERO_BYTES (RING_OFF + RING_BYTES)

// ---------------------------------------------------------------------------
// Kernel 1: bit-pack connectivity, word-major-transposed:
//   maskT2[w*NIPAD + i] bit (j&31), w=j>>5, set iff W[i,j] != 0.
// ---------------------------------------------------------------------------
__global__ void _Brunel_build_mask(const float* __restrict__ W,
                                   uint32_t* __restrict__ maskT2)
{
    int j = blockIdx.x * blockDim.x + threadIdx.x;   // presyn 0..5119
    int i = blockIdx.y;                              // postsyn row 0..4999
    int lane = threadIdx.x & 63;
    bool nz = false;
    if (j < NN) nz = (W[(size_t)i * NN + j] != 0.0f);
    unsigned long long m = __ballot(nz);
    if ((lane & 31) == 0 && j < NN) {
        uint32_t wd = (lane == 0) ? (uint32_t)m : (uint32_t)(m >> 32);
        maskT2[(size_t)(j >> 5) * NIPAD + i] = wd;
    }
}

// ---------------------------------------------------------------------------
// Kernel 2: persistent SNN sim = round 8 + pipelined staging (T14 split).
//  Per chunk m:
//   1. publish chunk m's spike words (prefetched last iter) -> s_spk, sync
//   2. poll barc[m-2] (writers of chunk m+1's slots; ~2 chunks stale ->
//      near-zero wait), sync, ISSUE LLC loads for chunk m+1 into regs
//   3. compute chunk m (popc inner loop, round 7/8 verbatim) -- the LLC
//      load latency hides under this
//   4. epilogue steps + ring stores; vmcnt(0) drain; arrive barc[m]
//  Chunks 0..2 publish nothing (s_spk init-zero = no recurrent input).
// ---------------------------------------------------------------------------
__global__ void __launch_bounds__(IPB, 1) _Brunel_persist(
    const float* __restrict__ ext,
    const uint32_t* __restrict__ maskT2,
    uint32_t* __restrict__ ring,
    int* __restrict__ barc,
    float* __restrict__ out_spk,
    float* __restrict__ out_vs)
{
    const int tx   = threadIdx.x;
    const int bb   = blockIdx.x;
    const int b    = bb / BPB;
    const int i    = (bb % BPB) * IPB + tx;
    const bool act = (i < NN);
    const int lane = tx & 63;

    __shared__ __align__(16) uint32_t s_mask[IPB][156];   // 159,744 B
    __shared__ uint32_t s_mask156[IPB];                   //   1,024 B
    __shared__ __align__(16) uint32_t s_spk[CH][RW];      //   2,560 B
    uint32_t* s_flat = (uint32_t*)s_spk;

    // ---- one-time: mask row -> LDS (global reads coalesced over tx) ----
    for (int w = 0; w < NW; ++w) {
        uint32_t mv = maskT2[(size_t)w * NIPAD + i];      // pad cols are 0
        if (w < 156) s_mask[tx][w] = mv; else s_mask156[tx] = mv;
    }
    for (int idx = tx; idx < CH * RW; idx += IPB) s_flat[idx] = 0u;
    __syncthreads();

    float v = 0.0f;
    uint64_t rAB = 0;          // prefetched spike words (flat 2tx, 2tx+1)
    uint32_t rC  = 0;          // prefetched spike word  (flat 512+tx, tx<128)

    for (int t0 = 0, m = 0; t0 < TSTEPS; t0 += CH, ++m) {
        // ---- prefetch external inputs for this chunk ----
        float x0 = 0.f, x1 = 0.f, x2 = 0.f, x3 = 0.f;
        if (act) {
            const float* e0 = ext + ((size_t)t0 * NB + b) * NN + i;
            const size_t st = (size_t)NB * NN;
            x0 = e0[0]; x1 = e0[st]; x2 = e0[2 * st]; x3 = e0[3 * st];
        }

        // ---- 1. publish chunk m's spike words (loaded during m-1) ----
        if (m >= 3) {
            ((uint64_t*)s_flat)[tx] = rAB;               // words 2tx, 2tx+1
            if (tx < CH * RW - 2 * IPB) s_flat[2 * IPB + tx] = rC; // 512+tx
            __syncthreads();
        }

        // ---- 2. poll for chunk m+1's writers, then issue LLC loads ----
        if (m >= 2 && m < NCHUNK - 1) {
            if (tx == 0) {
                const int* c3 = barc + (size_t)(m - 2) * BARSTRIDE;
                while (__hip_atomic_load(c3, __ATOMIC_RELAXED,
                                         __HIP_MEMORY_SCOPE_AGENT) < NBLK)
                    __builtin_amdgcn_s_sleep(2);
            }
            __syncthreads();                 // loads must not pass the poll
            const int ts0 = (t0 + CH) - NDELAY;   // chunk m+1's base ts
            {
                const int f = 2 * tx, k = f / RW, w = f - k * RW;
                const int ts = ts0 + k;
                const uint64_t* src = (const uint64_t*)
                    &ring[((size_t)(ts & (RING_SLOTS - 1)) * NB + b) * RW + w];
                rAB = __hip_atomic_load(src, __ATOMIC_RELAXED,
                                        __HIP_MEMORY_SCOPE_AGENT);
            }
            if (tx < CH * RW - 2 * IPB) {    // flat 512..639 -> k=3, w=32..159
                const int f = 2 * IPB + tx, k = f / RW, w = f - k * RW;
                const int ts = ts0 + k;
                rC = __hip_atomic_load(
                    &ring[((size_t)(ts & (RING_SLOTS - 1)) * NB + b) * RW + w],
                    __ATOMIC_RELAXED, __HIP_MEMORY_SCOPE_AGENT);
            }
        }

        // ---- 3. synapse counts: mask uint4 read ONCE, used for 4 steps ----
        int cE0 = 0, cE1 = 0, cE2 = 0, cE3 = 0;
        int cI0 = 0, cI1 = 0, cI2 = 0, cI3 = 0;
        const uint32_t* __restrict__ mrow = s_mask[tx];

#pragma unroll 4                       // bounded: no full-unroll spill
        for (int c = 0; c < 31; ++c) { // words 0..123: all excitatory
            uint4 m4 = *(const uint4*)(mrow + 4 * c);
            uint4 a0 = *(const uint4*)(&s_spk[0][4 * c]);
            uint4 a1 = *(const uint4*)(&s_spk[1][4 * c]);
            uint4 a2 = *(const uint4*)(&s_spk[2][4 * c]);
            uint4 a3 = *(const uint4*)(&s_spk[3][4 * c]);
            cE0 += __popc(m4.x & a0.x) + __popc(m4.y & a0.y)
                 + __popc(m4.z & a0.z) + __popc(m4.w & a0.w);
            cE1 += __popc(m4.x & a1.x) + __popc(m4.y & a1.y)
                 + __popc(m4.z & a1.z) + __popc(m4.w & a1.w);
            cE2 += __popc(m4.x & a2.x) + __popc(m4.y & a2.y)
                 + __popc(m4.z & a2.z) + __popc(m4.w & a2.w);
            cE3 += __popc(m4.x & a3.x) + __popc(m4.y & a3.y)
                 + __popc(m4.z & a3.z) + __popc(m4.w & a3.w);
        }
        {   // c = 31: word 124 excitatory, words 125..127 inhibitory
            uint4 m4 = *(const uint4*)(mrow + 124);
            uint4 a0 = *(const uint4*)(&s_spk[0][124]);
            uint4 a1 = *(const uint4*)(&s_spk[1][124]);
            uint4 a2 = *(const uint4*)(&s_spk[2][124]);
            uint4 a3 = *(const uint4*)(&s_spk[3][124]);
            cE0 += __popc(m4.x & a0.x);
            cI0 += __popc(m4.y & a0.y) + __popc(m4.z & a0.z) + __popc(m4.w & a0.w);
            cE1 += __popc(m4.x & a1.x);
            cI1 += __popc(m4.y & a1.y) + __popc(m4.z & a1.z) + __popc(m4.w & a1.w);
            cE2 += __popc(m4.x & a2.x);
            cI2 += __popc(m4.y & a2.y) + __popc(m4.z & a2.z) + __popc(m4.w & a2.w);
            cE3 += __popc(m4.x & a3.x);
            cI3 += __popc(m4.y & a3.y) + __popc(m4.z & a3.z) + __popc(m4.w & a3.w);
        }
#pragma unroll 4
        for (int c = 32; c < 39; ++c) { // words 128..155: all inhibitory
            uint4 m4 = *(const uint4*)(mrow + 4 * c);
            uint4 a0 = *(const uint4*)(&s_spk[0][4 * c]);
            uint4 a1 = *(const uint4*)(&s_spk[1][4 * c]);
            uint4 a2 = *(const uint4*)(&s_spk[2][4 * c]);
            uint4 a3 = *(const uint4*)(&s_spk[3][4 * c]);
            cI0 += __popc(m4.x & a0.x) + __popc(m4.y & a0.y)
                 + __popc(m4.z & a0.z) + __popc(m4.w & a0.w);
            cI1 += __popc(m4.x & a1.x) + __popc(m4.y & a1.y)
                 + __popc(m4.z & a1.z) + __popc(m4.w & a1.w);
            cI2 += __popc(m4.x & a2.x) + __popc(m4.y & a2.y)
                 + __popc(m4.z & a2.z) + __popc(m4.w & a2.w);
            cI3 += __popc(m4.x & a3.x) + __popc(m4.y & a3.y)
                 + __popc(m4.z & a3.z) + __popc(m4.w & a3.w);
        }
        {   // word 156 (inhibitory)
            uint32_t mL = s_mask156[tx];
            cI0 += __popc(mL & s_spk[0][156]);
            cI1 += __popc(mL & s_spk[1][156]);
            cI2 += __popc(mL & s_spk[2][156]);
            cI3 += __popc(mL & s_spk[3][156]);
        }

        // ---- 4. sequential neuron updates + ring publish ----
#define BRUNEL_STEP(kk, xk)                                                   \
        {                                                                     \
            const int t = t0 + kk;                                            \
            float cur = 0.1f * (float)cE##kk - 0.5f * (float)cI##kk;          \
            v = v * 0.95f + (cur + xk);                                       \
            bool s = act && (v >= 1.0f);                                      \
            float sflag = s ? 1.0f : 0.0f;                                    \
            float vout  = s ? 0.0f : v;                                       \
            if (act) {                                                        \
                size_t o = ((size_t)t * NB + b) * NN + i;                     \
                out_spk[o] = sflag;                                           \
                out_vs[o]  = vout;                                            \
            }                                                                 \
            v = vout;                                                         \
            unsigned long long bm = __ballot(s);                              \
            if ((lane & 31) == 0 && act) {                                    \
                uint32_t wd = (lane == 0) ? (uint32_t)bm : (uint32_t)(bm >> 32); \
                __hip_atomic_store(                                           \
                    &ring[((size_t)(t & (RING_SLOTS - 1)) * NB + b) * RW + (i >> 5)], \
                    wd, __ATOMIC_RELAXED, __HIP_MEMORY_SCOPE_AGENT);          \
            }                                                                 \
        }
        BRUNEL_STEP(0, x0)
        BRUNEL_STEP(1, x1)
        BRUNEL_STEP(2, x2)
        BRUNEL_STEP(3, x3)
#undef BRUNEL_STEP

        // ---- arrive: per-wave store drain, block barrier, relaxed add ----
        asm volatile("s_waitcnt vmcnt(0)" ::: "memory");  // ring stores at LLC
        __syncthreads();             // all waves drained; also guards s_spk
        if (tx == 0)
            __hip_atomic_fetch_add(barc + (size_t)m * BARSTRIDE, 1,
                                   __ATOMIC_RELAXED, __HIP_MEMORY_SCOPE_AGENT);
    }
}

// ---------------------------------------------------------------------------
extern "C" void kernel_launch(void* const* d_in, const int* in_sizes, int n_in,
                              void* d_out, int out_size, void* d_ws, size_t ws_size,
                              hipStream_t stream)
{
    const float* ext = (const float*)d_in[0];   // [T,B,N] fp32
    const float* W   = (const float*)d_in[1];   // [N,N]   fp32

    float* out_spk = (float*)d_out;                          // [T,B,N]
    float* out_vs  = out_spk + (size_t)TSTEPS * NB * NN;     // [T,B,N]

    uint8_t*  ws   = (uint8_t*)d_ws;
    uint32_t* mask = (uint32_t*)(ws);
    int*      barc = (int*)(ws + BAR_OFF);
    uint32_t* ring = (uint32_t*)(ws + RING_OFF);

    // zero mask (pad columns must read 0) + per-chunk counters + ring
    hipMemsetAsync(ws, 0, ZERO_BYTES, stream);

    dim3 gmask(NIPAD / IPB, NN);   // (20, 5000)
    _Brunel_build_mask<<<gmask, IPB, 0, stream>>>(W, mask);

    _Brunel_persist<<<NBLK, IPB, 0, stream>>>(ext, mask, ring, barc,
                                              out_spk, out_vs);
}